// Round 1
// 363.645 us; speedup vs baseline: 1.0200x; 1.0200x over previous
//
#include <hip/hip_runtime.h>

#define BB 4
#define SS 2048
#define DD 1024
#define HH 16
#define DKC 64
#define MT (BB*SS)   // 8192 rows total
#define NX (MT*DD)   // 8388608
#define NW (DD*DD)   // 1048576

typedef _Float16 f16x8 __attribute__((ext_vector_type(8)));
typedef _Float16 f16x4 __attribute__((ext_vector_type(4)));
typedef float f32x4 __attribute__((ext_vector_type(4)));
typedef int   i32x4 __attribute__((ext_vector_type(4)));

// async global->LDS, 16B per lane; LDS dest must be wave-uniform base + lane*16
#define GLDS16(g, l)                                                         \
  __builtin_amdgcn_global_load_lds(                                          \
      (__attribute__((address_space(1))) void*)(g),                          \
      (__attribute__((address_space(3))) void*)(l), 16, 0, 0)

// ---------------- fp32 -> fp16 conversion, one flat kernel over X(q,k,v)|W(q,k,v,o) ----------------
__global__ __launch_bounds__(256) void cvt_all(const float* __restrict__ xq,
                                               const float* __restrict__ xk,
                                               const float* __restrict__ xv,
                                               const float* __restrict__ wq,
                                               const float* __restrict__ wk,
                                               const float* __restrict__ wv,
                                               const float* __restrict__ wo,
                                               _Float16* __restrict__ dst) {
  size_t i = ((size_t)blockIdx.x * 256 + threadIdx.x) * 4;
  const float* src; size_t off;
  if (i < (size_t)NX)          { src = xq; off = i; }
  else if (i < (size_t)2*NX)   { src = xk; off = i - (size_t)NX; }
  else if (i < (size_t)3*NX)   { src = xv; off = i - (size_t)2*NX; }
  else {
    size_t j = i - (size_t)3*NX;
    if (j < (size_t)NW)        { src = wq; off = j; }
    else if (j < (size_t)2*NW) { src = wk; off = j - (size_t)NW; }
    else if (j < (size_t)3*NW) { src = wv; off = j - (size_t)2*NW; }
    else                       { src = wo; off = j - (size_t)3*NW; }
  }
  f32x4 f = *(const f32x4*)(src + off);
  f16x4 o;
#pragma unroll
  for (int j = 0; j < 4; ++j) o[j] = (_Float16)f[j];
  *(f16x4*)(dst + i) = o;
}

// ---------------- QKV projection: Y = X @ W^T + b ----------------
// R10: global_load_lds staging (2-phase, double-buffered LDS) replaces the
// reg round-trip. LDS dest is linear (lane*16); the frag-read bank swizzle
// ((r>>1)&3 on the 4 chunks of each 64B row) is carried by PRE-SWIZZLING the
// per-lane global source column (rule: swizzle both sides or neither).
// Q,K scatter to [B,H,S,DK]; V (z==2) scatters transposed AND key-permuted to
// [B,H,DK, tile(s)*64 + kappa] with kappa(key) = (key&15)*4 + (key>>4) so attn's
// P-store is a contiguous b64.
__global__ __launch_bounds__(256) void gemm_qkv(const _Float16* __restrict__ Xb,
                                                const _Float16* __restrict__ Wb,
                                                const float* __restrict__ b0,
                                                const float* __restrict__ b1,
                                                const float* __restrict__ b2,
                                                _Float16* __restrict__ Pj) {
  const int z = blockIdx.z;
  const _Float16* A = Xb + (size_t)z * MT * DD;
  const _Float16* W = Wb + (size_t)z * DD * DD;
  const float* bias = (z == 0) ? b0 : ((z == 1) ? b1 : b2);
  _Float16* out = Pj + (size_t)z * MT * DD;

  const int m0 = blockIdx.x * 128;   // m fastest -> XCD round-robin over m
  const int n0 = blockIdx.y * 128;
  const int t = threadIdx.x;
  const int lane = t & 63;
  const int wave = t >> 6;
  const int q = lane >> 4, r = lane & 15;
  const int wm = (wave & 1) * 64, wn = (wave >> 1) * 64;

  __shared__ __align__(16) _Float16 sA[2][128 * 32];
  __shared__ __align__(16) _Float16 sB[2][128 * 32];

  f32x4 acc[4][4] = {};

  const int row0 = t >> 2;
  const int csw = (t & 3) ^ ((t >> 3) & 3);  // pre-swizzled source chunk
  const int fsw = (r >> 1) & 3;              // frag-read swizzle

  auto stage = [&](int buf, int k0) {
#pragma unroll
    for (int i = 0; i < 2; ++i) {
      GLDS16(A + (size_t)(m0 + row0 + 64 * i) * DD + k0 + csw * 8,
             &sA[buf][(t + 256 * i) * 8]);
      GLDS16(W + (size_t)(n0 + row0 + 64 * i) * DD + k0 + csw * 8,
             &sB[buf][(t + 256 * i) * 8]);
    }
  };

  stage(0, 0);
  __syncthreads();                 // vmcnt(0) drain + barrier: buf0 ready

  int cur = 0;
  for (int k0 = 0; k0 < DD; k0 += 32) {
    if (k0 + 32 < DD) stage(cur ^ 1, k0 + 32);   // in flight across the MFMAs

    f16x8 af[4], bf[4];
#pragma unroll
    for (int x = 0; x < 4; ++x) {
      af[x] = *(const f16x8*)&sA[cur][(wm + x * 16 + r) * 32 + ((q ^ fsw) * 8)];
      bf[x] = *(const f16x8*)&sB[cur][(wn + x * 16 + r) * 32 + ((q ^ fsw) * 8)];
    }
#pragma unroll
    for (int mi = 0; mi < 4; ++mi)
#pragma unroll
      for (int ni = 0; ni < 4; ++ni)
        acc[mi][ni] = __builtin_amdgcn_mfma_f32_16x16x32_f16(af[mi], bf[ni], acc[mi][ni], 0, 0, 0);
    __syncthreads();               // drains next-tile loads; protects buffer reuse
    cur ^= 1;
  }

  // epilogue: C/D layout col=lane&15, row=(lane>>4)*4+reg
  if (z == 2) {
    // V^T + kappa permutation: [B,H,DK, (s&~63) + kappa(s&63)]
#pragma unroll
    for (int ni = 0; ni < 4; ++ni) {
      int gn = n0 + wn + ni * 16 + r;
      float bv = bias[gn];
      int h = gn >> 6, dk = gn & 63;
#pragma unroll
      for (int mi = 0; mi < 4; ++mi) {
        int gm = m0 + wm + mi * 16 + q * 4;
        int bb = gm >> 11, s0 = gm & 2047;
        int kl = s0 & 63;                       // kl % 4 == 0
        int kap0 = (kl & 15) * 4 + (kl >> 4);   // kappa of s0; +rr -> kap0+rr*4
        size_t base = ((size_t)((bb * HH + h) * DKC + dk)) * SS + (s0 - kl);
#pragma unroll
        for (int rr = 0; rr < 4; ++rr)
          out[base + kap0 + rr * 4] = (_Float16)(acc[mi][ni][rr] + bv);
      }
    }
  } else {
#pragma unroll
    for (int ni = 0; ni < 4; ++ni) {
      int gn = n0 + wn + ni * 16 + r;
      float bv = bias[gn];
      int h = gn >> 6, dk = gn & 63;
#pragma unroll
      for (int mi = 0; mi < 4; ++mi) {
#pragma unroll
        for (int rr = 0; rr < 4; ++rr) {
          int gm = m0 + wm + mi * 16 + q * 4 + rr;
          int bb = gm >> 11, s = gm & 2047;
          out[((size_t)((bb * HH + h) * SS + s)) * DKC + dk] = (_Float16)(acc[mi][ni][rr] + bv);
        }
      }
    }
  }
}

// ---------------- flash attention: one (b,h,q-tile of 128) per block ----------------
// R10: full-depth XOR swizzle on sVt and sP (was (row&1)<<2 granule -> 4-way
// bank conflict on every PV-path b128 read; SQ_LDS_BANK_CONFLICT 1.9e7).
// The packed b64 P-store stays conflict-free with granule g = (r>>1)^(prow&7):
// 16 lanes/pass cover all 32 banks exactly once. Reads use chunk^(row&7), same
// as sK. sMB stored as f16 (-30000 saturates exp2 to 0): LDS 40->36 KB.
__global__ __launch_bounds__(256) void attn(const _Float16* __restrict__ Pj,
                                            const int* __restrict__ mask,
                                            _Float16* __restrict__ Cx) {
  const int qt = blockIdx.x, h = blockIdx.y, bb = blockIdx.z;
  const size_t hoff = ((size_t)(bb * HH + h) * SS) * DKC;
  const _Float16* Qh  = Pj + hoff;
  const _Float16* Kh  = Pj + (size_t)MT * DD + hoff;
  const _Float16* Vth = Pj + (size_t)2 * MT * DD + hoff;  // [DK][tile*64+kappa]
  _Float16* Ch = Cx + hoff;
  const int* mrow = mask + bb * SS;

  const int t = threadIdx.x, lane = t & 63, wave = t >> 6;
  const int q = lane >> 4, r = lane & 15;
  const int qrow0 = qt * 128 + wave * 32;   // each wave owns 32 Q rows

  __shared__ __align__(16) _Float16 sK[64 * 64];      // [key][dk], chunk-xor swizzled
  __shared__ __align__(16) _Float16 sVt[64 * 64];     // [dk][kappa], chunk-xor swizzled
  __shared__ __align__(16) _Float16 sP[4][32 * 64];   // per-wave P [qrow][kappa], chunk-xor swizzled
  __shared__ __align__(16) _Float16 sMBh[SS];         // mask bias (0 / -30000), 4 KB

  // stage mask bias once: 2048 entries / 256 threads = 8 each
  {
    int i0 = t * 8;
    i32x4 m0v = *(const i32x4*)(mrow + i0);
    i32x4 m1v = *(const i32x4*)(mrow + i0 + 4);
    f16x8 bvv;
#pragma unroll
    for (int j = 0; j < 4; ++j) {
      bvv[j]     = m0v[j] ? (_Float16)0.0f : (_Float16)(-30000.0f);
      bvv[4 + j] = m1v[j] ? (_Float16)0.0f : (_Float16)(-30000.0f);
    }
    *(f16x8*)&sMBh[i0] = bvv;
  }

  // Q in registers as A-fragments: A[m=lane&15][k=quad*8+j]
  f16x8 qf[2][2];
#pragma unroll
  for (int mi = 0; mi < 2; ++mi)
#pragma unroll
    for (int kk = 0; kk < 2; ++kk)
      qf[mi][kk] = *(const f16x8*)&Qh[(size_t)(qrow0 + mi * 16 + r) * DKC + kk * 32 + q * 8];

  float lst[2][4] = {};           // lane-local partial row sums
  f32x4 oacc[2][4] = {};

  const float C2 = 0.125f * 1.44269504089f;  // log2(e)/sqrt(DK)

  // staging coords: 256 thr x 2 iters = 64 rows x 8 chunks of 16 B
  const int srow0 = t >> 3, scc = t & 7;

  // prefetch tile 0 into registers
  f16x8 kpre[2], vpre[2];
#pragma unroll
  for (int i = 0; i < 2; ++i) {
    int row = srow0 + 32 * i;
    kpre[i] = *(const f16x8*)(Kh + (size_t)row * DKC + scc * 8);
    vpre[i] = *(const f16x8*)(Vth + (size_t)row * SS + scc * 8);
  }

  for (int kt = 0; kt < SS; kt += 64) {
    // commit prefetched tile to LDS (full (row&7) granule xor on both arrays)
#pragma unroll
    for (int i = 0; i < 2; ++i) {
      int row = srow0 + 32 * i;
      *(f16x8*)&sK [row * 64 + ((scc ^ (row & 7)) << 3)] = kpre[i];
      *(f16x8*)&sVt[row * 64 + ((scc ^ (row & 7)) << 3)] = vpre[i];
    }
    __syncthreads();   // also covers sMBh visibility on first iteration

    // issue next tile's global loads now; vmcnt drains at the NEXT commit
    if (kt + 64 < SS) {
#pragma unroll
      for (int i = 0; i < 2; ++i) {
        int row = srow0 + 32 * i;
        kpre[i] = *(const f16x8*)(Kh + (size_t)(kt + 64 + row) * DKC + scc * 8);
        vpre[i] = *(const f16x8*)(Vth + (size_t)row * SS + kt + 64 + scc * 8);
      }
    }

    // scores = Q @ K^T
    f32x4 sacc[2][4] = {};
#pragma unroll
    for (int kk = 0; kk < 2; ++kk) {
      f16x8 kb[4];
#pragma unroll
      for (int ni = 0; ni < 4; ++ni)
        kb[ni] = *(const f16x8*)&sK[(ni * 16 + r) * 64 + (((kk * 4 + q) ^ (r & 7)) << 3)];
      __builtin_amdgcn_s_setprio(1);
#pragma unroll
      for (int mi = 0; mi < 2; ++mi)
#pragma unroll
        for (int ni = 0; ni < 4; ++ni)
          sacc[mi][ni] = __builtin_amdgcn_mfma_f32_16x16x32_f16(qf[mi][kk], kb[ni], sacc[mi][ni], 0, 0, 0);
      __builtin_amdgcn_s_setprio(0);
    }

    float mb[4];
#pragma unroll
    for (int ni = 0; ni < 4; ++ni) mb[ni] = (float)sMBh[kt + ni * 16 + r];  // LDS, lgkmcnt only

    // p = exp2(s*C2 + maskbias); packed store: kappa(key=ni*16+r) = r*4+ni ->
    // 4 contiguous f16 at granule (r>>1) of row prow, placed at g=(r>>1)^(prow&7)
#pragma unroll
    for (int mi = 0; mi < 2; ++mi) {
#pragma unroll
      for (int rr = 0; rr < 4; ++rr) {
        float pp[4];
#pragma unroll
        for (int ni = 0; ni < 4; ++ni)
          pp[ni] = __builtin_amdgcn_exp2f(__builtin_fmaf(sacc[mi][ni][rr], C2, mb[ni]));
        lst[mi][rr] += (pp[0] + pp[1]) + (pp[2] + pp[3]);
        int prow = mi * 16 + q * 4 + rr;
        int g = (r >> 1) ^ ((q * 4 + rr) & 7);       // (r>>1) ^ (prow&7)
        int goff = prow * 64 + (g << 3) + ((r & 1) << 2);
        unsigned lo = __builtin_bit_cast(unsigned, __builtin_amdgcn_cvt_pkrtz(pp[0], pp[1]));
        unsigned hi = __builtin_bit_cast(unsigned, __builtin_amdgcn_cvt_pkrtz(pp[2], pp[3]));
        uint2 u; u.x = lo; u.y = hi;
        *(uint2*)&sP[wave][goff] = u;
      }
    }
    __threadfence_block();  // wave-local LDS write->read ordering

    // O += P @ V   (contraction over kappa; P cols and V rows share the permutation)
#pragma unroll
    for (int kk = 0; kk < 2; ++kk) {
      f16x8 ap[2], vb[4];
#pragma unroll
      for (int mi = 0; mi < 2; ++mi)
        ap[mi] = *(const f16x8*)&sP[wave][(mi * 16 + r) * 64 + (((kk * 4 + q) ^ (r & 7)) << 3)];
#pragma unroll
      for (int ni = 0; ni < 4; ++ni)
        vb[ni] = *(const f16x8*)&sVt[(ni * 16 + r) * 64 + (((kk * 4 + q) ^ (r & 7)) << 3)];
      __builtin_amdgcn_s_setprio(1);
#pragma unroll
      for (int mi = 0; mi < 2; ++mi)
#pragma unroll
        for (int ni = 0; ni < 4; ++ni)
          oacc[mi][ni] = __builtin_amdgcn_mfma_f32_16x16x32_f16(ap[mi], vb[ni], oacc[mi][ni], 0, 0, 0);
      __builtin_amdgcn_s_setprio(0);
    }
    __syncthreads();
  }

  // epilogue: reduce row sums across the 16-lane r-groups, normalize, store
#pragma unroll
  for (int mi = 0; mi < 2; ++mi)
#pragma unroll
    for (int rr = 0; rr < 4; ++rr) {
      float l = lst[mi][rr];
#pragma unroll
      for (int d = 1; d < 16; d <<= 1) l += __shfl_xor(l, d);
      lst[mi][rr] = 1.0f / l;
    }

#pragma unroll
  for (int mi = 0; mi < 2; ++mi)
#pragma unroll
    for (int ni = 0; ni < 4; ++ni)
#pragma unroll
      for (int rr = 0; rr < 4; ++rr) {
        int row = qrow0 + mi * 16 + q * 4 + rr;
        Ch[(size_t)row * DKC + ni * 16 + r] = (_Float16)(oacc[mi][ni][rr] * lst[mi][rr]);
      }
}

// ---------------- output projection: out = ctx @ Wo^T + bo (fp32 out) ----------------
__global__ __launch_bounds__(256) void gemm_out(const _Float16* __restrict__ Cx,
                                                const _Float16* __restrict__ W,
                                                const float* __restrict__ bias,
                                                float* __restrict__ out) {
  const int m0 = blockIdx.x * 128;
  const int n0 = blockIdx.y * 128;
  const int t = threadIdx.x;
  const int lane = t & 63;
  const int wave = t >> 6;
  const int q = lane >> 4, r = lane & 15;
  const int wm = (wave & 1) * 64, wn = (wave >> 1) * 64;

  __shared__ __align__(16) _Float16 sA[2][128 * 32];
  __shared__ __align__(16) _Float16 sB[2][128 * 32];

  f32x4 acc[4][4] = {};

  const int row0 = t >> 2;
  const int csw = (t & 3) ^ ((t >> 3) & 3);
  const int fsw = (r >> 1) & 3;

  size_t abase[2];
#pragma unroll
  for (int i = 0; i < 2; ++i) {
    int gm = m0 + row0 + 64 * i;
    int bb = gm >> 11, s = gm & 2047;
    abase[i] = ((size_t)(bb * HH) * SS + s) * DKC;
  }

  auto stage = [&](int buf, int k0) {
    int head = k0 >> 6, off = (k0 & 63) + csw * 8;   // swizzled col stays in-head
#pragma unroll
    for (int i = 0; i < 2; ++i) {
      GLDS16(Cx + abase[i] + (size_t)head * SS * DKC + off,
             &sA[buf][(t + 256 * i) * 8]);
      GLDS16(W + (size_t)(n0 + row0 + 64 * i) * DD + k0 + csw * 8,
             &sB[buf][(t + 256 * i) * 8]);
    }
  };

  stage(0, 0);
  __syncthreads();

  int cur = 0;
  for (int k0 = 0; k0 < DD; k0 += 32) {
    if (k0 + 32 < DD) stage(cur ^ 1, k0 + 32);

    f16x8 af[4], bf[4];
#pragma unroll
    for (int x = 0; x < 4; ++x) {
      af[x] = *(const f16x8*)&sA[cur][(wm + x * 16 + r) * 32 + ((q ^ fsw) * 8)];
      bf[x] = *(const f16x8*)&sB[cur][(wn + x * 16 + r) * 32 + ((q ^ fsw) * 8)];
    }
#pragma unroll
    for (int mi = 0; mi < 4; ++mi)
#pragma unroll
      for (int ni = 0; ni < 4; ++ni)
        acc[mi][ni] = __builtin_amdgcn_mfma_f32_16x16x32_f16(af[mi], bf[ni], acc[mi][ni], 0, 0, 0);
    __syncthreads();
    cur ^= 1;
  }

#pragma unroll
  for (int ni = 0; ni < 4; ++ni) {
    int gn = n0 + wn + ni * 16 + r;
    float bv = bias[gn];
#pragma unroll
    for (int mi = 0; mi < 4; ++mi) {
#pragma unroll
      for (int rr = 0; rr < 4; ++rr) {
        int gm = m0 + wm + mi * 16 + q * 4 + rr;
        out[(size_t)gm * DD + gn] = acc[mi][ni][rr] + bv;
      }
    }
  }
}

extern "C" void kernel_launch(void* const* d_in, const int* in_sizes, int n_in,
                              void* d_out, int out_size, void* d_ws, size_t ws_size,
                              hipStream_t stream) {
  const float* query = (const float*)d_in[0];
  const float* key_  = (const float*)d_in[1];
  const float* value = (const float*)d_in[2];
  const int*   mask  = (const int*)d_in[3];
  const float* Wq = (const float*)d_in[4];
  const float* bq = (const float*)d_in[5];
  const float* Wk = (const float*)d_in[6];
  const float* bk = (const float*)d_in[7];
  const float* Wv = (const float*)d_in[8];
  const float* bv = (const float*)d_in[9];
  const float* Wo = (const float*)d_in[10];
  const float* bo = (const float*)d_in[11];
  float* out = (float*)d_out;

  // workspace layout (fp16): X(q,k,v) | W(q,k,v,o) | proj Q,K [B,H,S,DK] + Vpi [B,H,DK,S'] | ctx
  _Float16* Xb = (_Float16*)d_ws;
  _Float16* Wb = Xb + (size_t)3 * NX;
  _Float16* Pj = Wb + (size_t)4 * NW;
  _Float16* Cx = Pj + (size_t)3 * NX;

  cvt_all<<<(3 * NX + 4 * NW) / 1024, 256, 0, stream>>>(query, key_, value, Wq, Wk, Wv, Wo, Xb);

  gemm_qkv<<<dim3(MT / 128, DD / 128, 3), 256, 0, stream>>>(Xb, Wb, bq, bk, bv, Pj);
  attn<<<dim3(SS / 128, HH, BB), 256, 0, stream>>>(Pj, mask, Cx);
  gemm_out<<<dim3(MT / 128, DD / 128), 256, 0, stream>>>(Cx, Wb + (size_t)3 * NW, bo, out);
}